// Round 8
// baseline (293.098 us; speedup 1.0000x reference)
//
#include <hip/hip_runtime.h>
#include <cstdint>
#include <cmath>

// MultiHead attention fused pipeline for MI355X (gfx950).
// B=4, T=2048, E=1024, H=16, hs=64. fp32 in/out, bf16 MFMA compute.
// Round 6 kernel, third submission (two acquisition timeouts — never benched):
// attn barrier-free — no LDS, K/V fragments read per-wave directly from global
// (L2-resident per XCD), each wave loops only its own causal tile range.
// GEMM + cvt kernels unchanged from round 5 (attribution).

typedef __attribute__((ext_vector_type(8))) __bf16 bf16x8;
typedef __attribute__((ext_vector_type(4))) __bf16 bf16x4;
typedef __attribute__((ext_vector_type(4))) float f32x4;
typedef __attribute__((ext_vector_type(16))) float f32x16;

#define B_ 4
#define T_ 2048
#define E_ 1024
#define H_ 16
#define HS_ 64

__device__ __forceinline__ f32x4 mfma16(bf16x8 a, bf16x8 b, f32x4 c) {
  return __builtin_amdgcn_mfma_f32_16x16x32_bf16(a, b, c, 0, 0, 0);
}
__device__ __forceinline__ f32x16 mfma32(bf16x8 a, bf16x8 b, f32x16 c) {
  return __builtin_amdgcn_mfma_f32_32x32x16_bf16(a, b, c, 0, 0, 0);
}

__device__ __forceinline__ void gload_lds16(const void* g, void* l) {
  __builtin_amdgcn_global_load_lds(
      (const __attribute__((address_space(1))) unsigned int*)g,
      (__attribute__((address_space(3))) unsigned int*)l,
      16, 0, 0);
}

__device__ __forceinline__ unsigned cvt_pk_bf16(float lo, float hi) {
  unsigned r;
  asm("v_cvt_pk_bf16_f32 %0, %1, %2" : "=v"(r) : "v"(lo), "v"(hi));
  return r;
}
__device__ __forceinline__ void pl32swap(unsigned& a, unsigned& b) {
  asm("v_permlane32_swap_b32 %0, %1" : "+v"(a), "+v"(b));
}
__device__ __forceinline__ void barrier_asm() {
  asm volatile("s_barrier" ::: "memory");
}

// ---- convert x (fp32) -> Xb (bf16) ----
__global__ __launch_bounds__(256) void cvt_x_kernel(const float* __restrict__ x,
                                                    __bf16* __restrict__ xb) {
  int i = (blockIdx.x * 256 + threadIdx.x) * 4;
  float4 v = *(const float4*)(x + i);
  bf16x4 o;
  o[0] = (__bf16)v.x; o[1] = (__bf16)v.y; o[2] = (__bf16)v.z; o[3] = (__bf16)v.w;
  *(bf16x4*)(xb + i) = o;
}

// ---- W[h][e][d] (fp32) -> Wt[qkv][n=h*64+d][e] (bf16, B^T layout) ----
__global__ __launch_bounds__(256) void cvt_w_kernel(const float* __restrict__ Wq,
                                                    const float* __restrict__ Wk,
                                                    const float* __restrict__ Wv,
                                                    __bf16* __restrict__ wt) {
  __shared__ float tile[64][65];
  const int e0 = blockIdx.x * 64;
  const int h = blockIdx.y;
  const int qkv = blockIdx.z;
  const int t = threadIdx.x;
  const float* W = (qkv == 0) ? Wq : (qkv == 1) ? Wk : Wv;
#pragma unroll
  for (int j = 0; j < 4; ++j) {
    int idx = j * 256 + t;
    int d4 = idx & 15, e = idx >> 4;
    float4 v = *(const float4*)&W[((size_t)(h * 1024 + e0 + e)) * 64 + d4 * 4];
    tile[d4 * 4 + 0][e] = v.x;
    tile[d4 * 4 + 1][e] = v.y;
    tile[d4 * 4 + 2][e] = v.z;
    tile[d4 * 4 + 3][e] = v.w;
  }
  __syncthreads();
#pragma unroll
  for (int j = 0; j < 2; ++j) {
    int idx = j * 256 + t;
    int e8 = idx & 7, d = idx >> 3;
    bf16x8 o;
#pragma unroll
    for (int i = 0; i < 8; ++i) o[i] = (__bf16)tile[d][e8 * 8 + i];
    *(bf16x8*)&wt[((size_t)qkv << 20) + (size_t)(h * 64 + d) * 1024 + e0 + e8 * 8] = o;
  }
}

// ---- QKV projection GEMM: 128x128 tile, BK=32, 4 waves.
//      3-slot counted-vmcnt pipeline (depth-2), 48KB LDS -> 3 blocks/CU. ----
__global__ __launch_bounds__(256) void qkv_gemm_kernel(
    const __bf16* __restrict__ Xb, const __bf16* __restrict__ Wt,
    __bf16* __restrict__ Qb, __bf16* __restrict__ Kb, __bf16* __restrict__ Vt) {
  __shared__ __bf16 As[3][128 * 32];
  __shared__ __bf16 Bs[3][128 * 32];
  const int qkv = blockIdx.z;
  const int m0 = blockIdx.x * 128;
  const int n0 = blockIdx.y * 128;
  const int t = threadIdx.x;
  const int lane = t & 63;
  const int w = t >> 6, wr = w >> 1, wc = w & 1;
  const int g = lane >> 4, c = lane & 15;

  const __bf16* wsrc = Wt + ((size_t)qkv << 20);
  f32x4 acc[4][4] = {};

  const int srow = t >> 2;
  const int cs8 = (((t & 3) ^ (srow & 3)) << 3);
  const __bf16* gA0 = Xb + (size_t)(m0 + srow) * 1024 + cs8;
  const __bf16* gA1 = Xb + (size_t)(m0 + 64 + srow) * 1024 + cs8;
  const __bf16* gB0 = wsrc + (size_t)(n0 + srow) * 1024 + cs8;
  const __bf16* gB1 = wsrc + (size_t)(n0 + 64 + srow) * 1024 + cs8;

  auto stage = [&](int s, int slot) {
    const int ko = s * 32;
    gload_lds16(gA0 + ko, &As[slot][t * 8]);
    gload_lds16(gA1 + ko, &As[slot][2048 + t * 8]);
    gload_lds16(gB0 + ko, &Bs[slot][t * 8]);
    gload_lds16(gB1 + ko, &Bs[slot][2048 + t * 8]);
  };

  stage(0, 0);
  stage(1, 1);  // 8 loads in flight

  const int gx = (g ^ (c & 3)) << 3;  // read-side swizzle (row&3 == c&3)
  int slot = 0;

#pragma unroll 1
  for (int kt = 0; kt < 32; ++kt) {
    if (kt < 31) {
      asm volatile("s_waitcnt vmcnt(4)" ::: "memory");
    } else {
      asm volatile("s_waitcnt vmcnt(0)" ::: "memory");
    }
    __builtin_amdgcn_sched_barrier(0);
    barrier_asm();  // tile kt resident in all waves' view; iter kt-1 reads done
    if (kt + 2 < 32) {
      int ns = slot + 2; if (ns >= 3) ns -= 3;
      stage(kt + 2, ns);
    }

    const __bf16* Ab = &As[slot][0];
    const __bf16* Bb = &Bs[slot][0];
    bf16x8 af[4], bfr[4];
#pragma unroll
    for (int mi = 0; mi < 4; ++mi)
      af[mi] = *(const bf16x8*)&Ab[(wr * 64 + mi * 16 + c) * 32 + gx];
#pragma unroll
    for (int ni = 0; ni < 4; ++ni)
      bfr[ni] = *(const bf16x8*)&Bb[(wc * 64 + ni * 16 + c) * 32 + gx];
    __builtin_amdgcn_s_setprio(1);
#pragma unroll
    for (int mi = 0; mi < 4; ++mi)
#pragma unroll
      for (int ni = 0; ni < 4; ++ni)
        acc[mi][ni] = mfma16(af[mi], bfr[ni], acc[mi][ni]);
    __builtin_amdgcn_s_setprio(0);
    __builtin_amdgcn_sched_barrier(0);
    slot = (slot == 2) ? 0 : slot + 1;
  }

  const int mbase = m0 + wr * 64 + g * 4;
  const int nbase = n0 + wc * 64 + c;
  if (qkv < 2) {
    __bf16* dst = (qkv == 0) ? Qb : Kb;  // [B][H][T][64]
#pragma unroll
    for (int mi = 0; mi < 4; ++mi) {
#pragma unroll
      for (int ni = 0; ni < 4; ++ni) {
        int n = nbase + ni * 16;
        int h = n >> 6, d = n & 63;
#pragma unroll
        for (int r = 0; r < 4; ++r) {
          int m = mbase + mi * 16 + r;
          int b = m >> 11, tt = m & 2047;
          dst[(((size_t)b * H_ + h) * T_ + tt) * HS_ + d] = (__bf16)acc[mi][ni][r];
        }
      }
    }
  } else {
    // V stored transposed: Vt[B][H][d][t]
#pragma unroll
    for (int mi = 0; mi < 4; ++mi) {
      int m = mbase + mi * 16;
      int b = m >> 11, tt = m & 2047;
#pragma unroll
      for (int ni = 0; ni < 4; ++ni) {
        int n = nbase + ni * 16;
        int h = n >> 6, d = n & 63;
        bf16x4 pk;
        pk[0] = (__bf16)acc[mi][ni][0];
        pk[1] = (__bf16)acc[mi][ni][1];
        pk[2] = (__bf16)acc[mi][ni][2];
        pk[3] = (__bf16)acc[mi][ni][3];
        *(bf16x4*)&Vt[(((size_t)b * H_ + h) * HS_ + d) * T_ + tt] = pk;
      }
    }
  }
}

// ---- fused causal attention, barrier-free ----
// 1024 blocks x 256 threads (4 waves). Block = (bh, 128-row q-tile); wave owns
// 32 q-rows and loops over ITS OWN causal kv-tile range — no LDS, no barriers.
// K/V fragments are read per-lane directly from global (L2-resident; all 16
// blocks of a bh land on one XCD via bh = j&63). Swapped QK^T (lane holds a
// P^T column), in-register softmax + cvt_pk/permlane32 P, PV as D[d][tq].
// qt order: stride-256 block groups {15-i, i, 11-i, 4+i} sum to 34 tiles.
__global__ __launch_bounds__(256) void attn_kernel(
    const __bf16* __restrict__ Qb, const __bf16* __restrict__ Kb,
    const __bf16* __restrict__ Vt, float* __restrict__ out) {
  const int j = blockIdx.x;
  const int bh = j & 63;
  const int qs = j >> 6;
  const int gq = qs >> 2, iq = qs & 3;
  const int qt = (gq == 0) ? 15 - iq : (gq == 1) ? iq : (gq == 2) ? 11 - iq : 4 + iq;
  const int b = bh >> 4, hh = bh & 15;
  const int t = threadIdx.x;
  const int lane = t & 63, w = t >> 6;
  const int lr = lane & 31, h = lane >> 5;

  const __bf16* Qg = Qb + (size_t)bh * T_ * HS_;
  const __bf16* Kg = Kb + (size_t)bh * T_ * HS_;
  const __bf16* Vg = Vt + (size_t)bh * HS_ * T_;

  const float C2 = 0.04508422f;  // log2(e)/32  (1/sqrt(E) folded into exp2)

  const int wrow = qt * 128 + w * 32;   // wave's first q-row
  const int tqg = wrow + lr;            // this lane's q-row (P^T column)
  const int NTw = wrow / 64 + 1;        // causal kv-tiles for this wave

  const __bf16* Qrow = Qg + (size_t)tqg * 64;
  bf16x8 qf[4];
#pragma unroll
  for (int ds = 0; ds < 4; ++ds)
    qf[ds] = *(const bf16x8*)(Qrow + ds * 16 + h * 8);

  f32x16 o0 = {}, o1 = {};
  float m_run = -INFINITY, l_run = 0.f;

#pragma unroll 1
  for (int kt = 0; kt < NTw; ++kt) {
    const int kbase = kt * 64;

    // --- K fragments from global: rows tk = kbase+lr / +32+lr, d = ds*16+h*8 ---
    const __bf16* Kr0 = Kg + (size_t)(kbase + lr) * 64 + h * 8;
    const __bf16* Kr1 = Kr0 + 32 * 64;
    bf16x8 kf0[4], kf1[4];
#pragma unroll
    for (int ds = 0; ds < 4; ++ds) {
      kf0[ds] = *(const bf16x8*)(Kr0 + ds * 16);
      kf1[ds] = *(const bf16x8*)(Kr1 + ds * 16);
    }

    // --- QK^T (swapped): S^T[tk][tq] ---
    f32x16 s0 = {}, s1 = {};
#pragma unroll
    for (int ds = 0; ds < 4; ++ds) {
      s0 = mfma32(kf0[ds], qf[ds], s0);
      s1 = mfma32(kf1[ds], qf[ds], s1);
    }

    // --- V fragments (issued now; land during softmax): rows d = lr / lr+32 ---
    const __bf16* Vr0 = Vg + (size_t)lr * (size_t)T_ + kbase + h * 8;
    const __bf16* Vr1 = Vr0 + (size_t)32 * T_;
    bf16x8 vf0[4], vf1[4];
#pragma unroll
    for (int blk = 0; blk < 4; ++blk) {
      vf0[blk] = *(const bf16x8*)(Vr0 + blk * 16);
      vf1[blk] = *(const bf16x8*)(Vr1 + blk * 16);
    }

    // --- causal mask (diagonal tiles only) ---
    if (kbase + 63 > wrow) {
#pragma unroll
      for (int r = 0; r < 16; ++r) {
        int tk0 = kbase + (r & 3) + 8 * (r >> 2) + 4 * h;
        if (tk0 > tqg) s0[r] = -INFINITY;
        if (tk0 + 32 > tqg) s1[r] = -INFINITY;
      }
    }

    // --- online softmax with defer-max (T13) ---
    float mx = s0[0];
#pragma unroll
    for (int r = 1; r < 16; ++r) mx = fmaxf(mx, s0[r]);
#pragma unroll
    for (int r = 0; r < 16; ++r) mx = fmaxf(mx, s1[r]);
    mx = fmaxf(mx, __shfl_xor(mx, 32));
    if (!__all(mx - m_run <= 256.f)) {
      float mn = fmaxf(m_run, mx);
      float fac = __builtin_amdgcn_exp2f((m_run - mn) * C2);
      l_run *= fac;
#pragma unroll
      for (int r = 0; r < 16; ++r) { o0[r] *= fac; o1[r] *= fac; }
      m_run = mn;
    }
    float sum = 0.f;
#pragma unroll
    for (int r = 0; r < 16; ++r) {
      s0[r] = __builtin_amdgcn_exp2f((s0[r] - m_run) * C2);
      s1[r] = __builtin_amdgcn_exp2f((s1[r] - m_run) * C2);
      sum += s0[r] + s1[r];
    }
    sum += __shfl_xor(sum, 32);
    l_run += sum;

    // --- P -> bf16 B-frags (cvt_pk + permlane32_swap), PV: D[d][tq] ---
#pragma unroll
    for (int blk = 0; blk < 4; ++blk) {
      f32x16& sv = (blk < 2) ? s0 : s1;
      const int off = (blk & 1) * 8;
      unsigned u0 = cvt_pk_bf16(sv[off + 0], sv[off + 1]);
      unsigned u1 = cvt_pk_bf16(sv[off + 2], sv[off + 3]);
      unsigned u2 = cvt_pk_bf16(sv[off + 4], sv[off + 5]);
      unsigned u3 = cvt_pk_bf16(sv[off + 6], sv[off + 7]);
      pl32swap(u0, u2);
      pl32swap(u1, u3);
      union { unsigned u[4]; bf16x8 v; } pb;
      pb.u[0] = u0; pb.u[1] = u1; pb.u[2] = u2; pb.u[3] = u3;
      o0 = mfma32(vf0[blk], pb.v, o0);
      o1 = mfma32(vf1[blk], pb.v, o1);
    }
  }

  // --- epilogue: O[d][tq] regs -> out[b][tq][hh*64+d] ---
  const float inv_l = 1.0f / l_run;
  float* orow = out + ((size_t)b * T_ + tqg) * E_ + hh * 64;
#pragma unroll
  for (int d0i = 0; d0i < 2; ++d0i) {
#pragma unroll
    for (int qd = 0; qd < 4; ++qd) {
      float4 v;
      const f32x16& ac = d0i ? o1 : o0;
      v.x = ac[qd * 4 + 0] * inv_l;
      v.y = ac[qd * 4 + 1] * inv_l;
      v.z = ac[qd * 4 + 2] * inv_l;
      v.w = ac[qd * 4 + 3] * inv_l;
      *(float4*)(orow + d0i * 32 + qd * 8 + 4 * h) = v;
    }
  }
}

extern "C" void kernel_launch(void* const* d_in, const int* in_sizes, int n_in,
                              void* d_out, int out_size, void* d_ws, size_t ws_size,
                              hipStream_t stream) {
  const float* x = (const float*)d_in[0];
  const float* Wq = (const float*)d_in[1];
  const float* Wk = (const float*)d_in[2];
  const float* Wv = (const float*)d_in[3];
  float* out = (float*)d_out;

  char* ws = (char*)d_ws;
  __bf16* Xb = (__bf16*)ws;                    // 16 MiB
  __bf16* Wt = (__bf16*)(ws + (16u << 20));    //  6 MiB
  __bf16* Qb = (__bf16*)(ws + (22u << 20));    // 16 MiB
  __bf16* Kb = (__bf16*)(ws + (38u << 20));    // 16 MiB
  __bf16* Vt = (__bf16*)(ws + (54u << 20));    // 16 MiB

  cvt_x_kernel<<<8192, 256, 0, stream>>>(x, Xb);
  cvt_w_kernel<<<dim3(16, 16, 3), 256, 0, stream>>>(Wq, Wk, Wv, Wt);
  qkv_gemm_kernel<<<dim3(64, 8, 3), 256, 0, stream>>>(Xb, Wt, Qb, Kb, Vt);
  attn_kernel<<<dim3(1024), 256, 0, stream>>>(Qb, Kb, Vt, out);
}

// Round 9
// 222.571 us; speedup vs baseline: 1.3169x; 1.3169x over previous
//
#include <hip/hip_runtime.h>
#include <cstdint>
#include <cmath>

// MultiHead attention fused pipeline for MI355X (gfx950).
// B=4, T=2048, E=1024, H=16, hs=64. fp32 in/out, bf16 MFMA compute.
// Round 9: attn reverted to round-5 (best measured; barrier-free experiment
// regressed 2x — uncoalesced per-lane K/V reads). qkv_gemm rewritten as
// m201-derived pipeline: BM=128 BN=256 BK=64, 8 waves, 2 phases/K-tile,
// counted vmcnt(4) (never 0 mid-loop), XOR-swizzled dbuf LDS, even 768 grid.

typedef __attribute__((ext_vector_type(8))) __bf16 bf16x8;
typedef __attribute__((ext_vector_type(4))) __bf16 bf16x4;
typedef __attribute__((ext_vector_type(4))) float f32x4;
typedef __attribute__((ext_vector_type(16))) float f32x16;

#define B_ 4
#define T_ 2048
#define E_ 1024
#define H_ 16
#define HS_ 64

__device__ __forceinline__ f32x4 mfma16(bf16x8 a, bf16x8 b, f32x4 c) {
  return __builtin_amdgcn_mfma_f32_16x16x32_bf16(a, b, c, 0, 0, 0);
}
__device__ __forceinline__ f32x16 mfma32(bf16x8 a, bf16x8 b, f32x16 c) {
  return __builtin_amdgcn_mfma_f32_32x32x16_bf16(a, b, c, 0, 0, 0);
}

__device__ __forceinline__ void gload_lds16(const void* g, void* l) {
  __builtin_amdgcn_global_load_lds(
      (const __attribute__((address_space(1))) unsigned int*)g,
      (__attribute__((address_space(3))) unsigned int*)l,
      16, 0, 0);
}

__device__ __forceinline__ unsigned cvt_pk_bf16(float lo, float hi) {
  unsigned r;
  asm("v_cvt_pk_bf16_f32 %0, %1, %2" : "=v"(r) : "v"(lo), "v"(hi));
  return r;
}
__device__ __forceinline__ void pl32swap(unsigned& a, unsigned& b) {
  asm("v_permlane32_swap_b32 %0, %1" : "+v"(a), "+v"(b));
}
__device__ __forceinline__ void barrier_asm() {
  asm volatile("s_barrier" ::: "memory");
}

// ---- convert x (fp32) -> Xb (bf16) ----
__global__ __launch_bounds__(256) void cvt_x_kernel(const float* __restrict__ x,
                                                    __bf16* __restrict__ xb) {
  int i = (blockIdx.x * 256 + threadIdx.x) * 4;
  float4 v = *(const float4*)(x + i);
  bf16x4 o;
  o[0] = (__bf16)v.x; o[1] = (__bf16)v.y; o[2] = (__bf16)v.z; o[3] = (__bf16)v.w;
  *(bf16x4*)(xb + i) = o;
}

// ---- W[h][e][d] (fp32) -> Wt[qkv][n=h*64+d][e] (bf16, B^T layout) ----
__global__ __launch_bounds__(256) void cvt_w_kernel(const float* __restrict__ Wq,
                                                    const float* __restrict__ Wk,
                                                    const float* __restrict__ Wv,
                                                    __bf16* __restrict__ wt) {
  __shared__ float tile[64][65];
  const int e0 = blockIdx.x * 64;
  const int h = blockIdx.y;
  const int qkv = blockIdx.z;
  const int t = threadIdx.x;
  const float* W = (qkv == 0) ? Wq : (qkv == 1) ? Wk : Wv;
#pragma unroll
  for (int j = 0; j < 4; ++j) {
    int idx = j * 256 + t;
    int d4 = idx & 15, e = idx >> 4;
    float4 v = *(const float4*)&W[((size_t)(h * 1024 + e0 + e)) * 64 + d4 * 4];
    tile[d4 * 4 + 0][e] = v.x;
    tile[d4 * 4 + 1][e] = v.y;
    tile[d4 * 4 + 2][e] = v.z;
    tile[d4 * 4 + 3][e] = v.w;
  }
  __syncthreads();
#pragma unroll
  for (int j = 0; j < 2; ++j) {
    int idx = j * 256 + t;
    int e8 = idx & 7, d = idx >> 3;
    bf16x8 o;
#pragma unroll
    for (int i = 0; i < 8; ++i) o[i] = (__bf16)tile[d][e8 * 8 + i];
    *(bf16x8*)&wt[((size_t)qkv << 20) + (size_t)(h * 64 + d) * 1024 + e0 + e8 * 8] = o;
  }
}

// ---- QKV projection GEMM: BM=128, BN=256, BK=64, 8 waves (2M x 4N).
//      Per-wave 64x64 output (acc 4x4). 2 phases per K-tile:
//      p0: {stage B(t+1) | vmcnt(4) | barrier | ds_read kh0 | 16 MFMA | barrier}
//      p1: {ds_read kh1 | stage A(t+1) | barrier | 16 MFMA | barrier}
//      Dbuf LDS 96KB, 8-slot XOR swizzle (pre-swizzled source, rule 21). ----
__global__ __launch_bounds__(512) void qkv_gemm_kernel(
    const __bf16* __restrict__ Xb, const __bf16* __restrict__ Wt,
    __bf16* __restrict__ Qb, __bf16* __restrict__ Kb, __bf16* __restrict__ Vt) {
  __shared__ __bf16 As[2 * 128 * 64];   // 32 KB  (buf stride 16384 B)
  __shared__ __bf16 Bs[2 * 256 * 64];   // 64 KB  (buf stride 32768 B)
  const int qkv = blockIdx.z;
  const int m0 = blockIdx.x * 128;
  const int n0 = blockIdx.y * 256;
  const int t = threadIdx.x;
  const int lane = t & 63;
  const int wid = t >> 6;
  const int wm = wid >> 2, wn = wid & 3;
  const int c = lane & 15, g = lane >> 4;

  const __bf16* wsrc = Wt + ((size_t)qkv << 20);
  f32x4 acc[4][4] = {};

  // staging: thread t covers LDS rows r0 (+64, ...) slot sl; source col is
  // pre-swizzled so linear dest + swizzled read form the same involution.
  const int r0 = t >> 3;                 // 0..63
  const int sl = t & 7;
  const int swz = ((sl ^ (r0 & 7)) * 8); // element offset within 64-elem row
  const __bf16* gA = Xb + (size_t)(m0 + r0) * 1024 + swz;
  const __bf16* gB = wsrc + (size_t)(n0 + r0) * 1024 + swz;

  auto stageA = [&](int tt, int buf) {   // 128 rows -> 2 loads
    const int ko = tt * 64;
    char* dst = (char*)As + buf * 16384 + t * 16;
    gload_lds16(gA + ko, dst);
    gload_lds16(gA + 64 * 1024 + ko, dst + 8192);
  };
  auto stageB = [&](int tt, int buf) {   // 256 rows -> 4 loads
    const int ko = tt * 64;
    char* dst = (char*)Bs + buf * 32768 + t * 16;
#pragma unroll
    for (int q = 0; q < 4; ++q)
      gload_lds16(gB + q * 64 * 1024 + ko, dst + q * 8192);
  };

  // read-side addresses: row r -> byte r*128 + ((kh*4+g) ^ (r&7))*16; r&7 == c&7
  const int cz = c & 7;
  const int sw0 = ((0 + g) ^ cz) * 16;
  const int sw1 = ((4 + g) ^ cz) * 16;
  const int arow = (wm * 64 + c) * 128;  // + i*2048
  const int brow = (wn * 64 + c) * 128;  // + j*2048

  // prologue: tile 0 fully staged (6 loads in flight)
  stageB(0, 0);
  stageA(0, 0);

#pragma unroll 1
  for (int tt = 0; tt < 16; ++tt) {
    const int buf = tt & 1;
    const bool pre = (tt + 1 < 16);
    const char* AsB = (const char*)As + buf * 16384;
    const char* BsB = (const char*)Bs + buf * 32768;

    // ---- phase 0 (kh = 0) ----
    if (pre) {
      stageB(tt + 1, buf ^ 1);
      asm volatile("s_waitcnt vmcnt(4)" ::: "memory");  // tile tt resident
    } else {
      asm volatile("s_waitcnt vmcnt(0)" ::: "memory");
    }
    barrier_asm();  // all waves: tile tt resident; prev reads of buf^1 done
    {
      bf16x8 aF[4], bF[4];
#pragma unroll
      for (int i = 0; i < 4; ++i)
        aF[i] = *(const bf16x8*)(AsB + arow + i * 2048 + sw0);
#pragma unroll
      for (int jj = 0; jj < 4; ++jj)
        bF[jj] = *(const bf16x8*)(BsB + brow + jj * 2048 + sw0);
      __builtin_amdgcn_s_setprio(1);
#pragma unroll
      for (int i = 0; i < 4; ++i)
#pragma unroll
        for (int jj = 0; jj < 4; ++jj)
          acc[i][jj] = mfma16(aF[i], bF[jj], acc[i][jj]);
      __builtin_amdgcn_s_setprio(0);
    }
    barrier_asm();

    // ---- phase 1 (kh = 1) ----
    {
      bf16x8 aF[4], bF[4];
#pragma unroll
      for (int i = 0; i < 4; ++i)
        aF[i] = *(const bf16x8*)(AsB + arow + i * 2048 + sw1);
#pragma unroll
      for (int jj = 0; jj < 4; ++jj)
        bF[jj] = *(const bf16x8*)(BsB + brow + jj * 2048 + sw1);
      if (pre) stageA(tt + 1, buf ^ 1);
      barrier_asm();
      __builtin_amdgcn_s_setprio(1);
#pragma unroll
      for (int i = 0; i < 4; ++i)
#pragma unroll
        for (int jj = 0; jj < 4; ++jj)
          acc[i][jj] = mfma16(aF[i], bF[jj], acc[i][jj]);
      __builtin_amdgcn_s_setprio(0);
    }
    barrier_asm();
  }

  // ---- epilogue ----
  const int mbase = m0 + wm * 64 + g * 4;
  const int nbase = n0 + wn * 64 + c;
  if (qkv < 2) {
    __bf16* dst = (qkv == 0) ? Qb : Kb;  // [B][H][T][64]
#pragma unroll
    for (int mi = 0; mi < 4; ++mi) {
#pragma unroll
      for (int ni = 0; ni < 4; ++ni) {
        int n = nbase + ni * 16;
        int h = n >> 6, d = n & 63;
#pragma unroll
        for (int r = 0; r < 4; ++r) {
          int m = mbase + mi * 16 + r;
          int b = m >> 11, tt2 = m & 2047;
          dst[(((size_t)b * H_ + h) * T_ + tt2) * HS_ + d] = (__bf16)acc[mi][ni][r];
        }
      }
    }
  } else {
    // V stored transposed: Vt[B][H][d][t]
#pragma unroll
    for (int mi = 0; mi < 4; ++mi) {
      int m = mbase + mi * 16;
      int b = m >> 11, tt2 = m & 2047;
#pragma unroll
      for (int ni = 0; ni < 4; ++ni) {
        int n = nbase + ni * 16;
        int h = n >> 6, d = n & 63;
        bf16x4 pk;
        pk[0] = (__bf16)acc[mi][ni][0];
        pk[1] = (__bf16)acc[mi][ni][1];
        pk[2] = (__bf16)acc[mi][ni][2];
        pk[3] = (__bf16)acc[mi][ni][3];
        *(bf16x4*)&Vt[(((size_t)b * H_ + h) * HS_ + d) * T_ + tt2] = pk;
      }
    }
  }
}

// ---- fused causal attention (round-5 version, best measured) ----
// 512 blocks x 512 threads; block = (bh, one 256-row q-tile). 8 waves x 32 rows.
// 3-slot counted-vmcnt K/V pipeline: 1 barrier/tile, no mid-loop vmcnt(0).
__global__ __launch_bounds__(512) void attn_kernel(
    const __bf16* __restrict__ Qb, const __bf16* __restrict__ Kb,
    const __bf16* __restrict__ Vt, float* __restrict__ out) {
  __shared__ __bf16 Ks[3][64 * 64];
  __shared__ __bf16 Vs[3][64 * 64];

  const int j = blockIdx.x;
  const int g8 = j >> 6;
  const int qt = (g8 < 4) ? (7 - g8) : (g8 - 4);
  const int bh = j & 63;
  const int b = bh >> 4, hh = bh & 15;
  const int t = threadIdx.x;
  const int lane = t & 63, w = t >> 6;
  const int lr = lane & 31, h = lane >> 5;

  const __bf16* Qg = Qb + (size_t)bh * T_ * HS_;
  const __bf16* Kg = Kb + (size_t)bh * T_ * HS_;
  const __bf16* Vg = Vt + (size_t)bh * HS_ * T_;

  const int srow = t >> 3;
  const int scb = ((t & 7) << 4) ^ ((srow & 7) << 4);   // pre-swizzled src col
  const int kxor = (lr & 7) << 4;                       // read-side swizzle

  auto stageKV = [&](int s, int slot) {
    gload_lds16((const char*)Kg + (size_t)(s * 64 + srow) * 128 + scb,
                (char*)&Ks[slot][0] + t * 16);
    gload_lds16((const char*)Vg + (size_t)srow * 4096 + s * 128 + scb,
                (char*)&Vs[slot][0] + t * 16);
  };

  const float C2 = 0.04508422f;  // log2(e)/32

  const int qbase = qt * 256;
  const int NT = (qt + 1) * 4;
  const int tqg = qbase + w * 32 + lr;

  const __bf16* Qrow = Qg + (size_t)tqg * 64;
  bf16x8 qf0 = *(const bf16x8*)(Qrow + h * 8);
  bf16x8 qf1 = *(const bf16x8*)(Qrow + 16 + h * 8);
  bf16x8 qf2 = *(const bf16x8*)(Qrow + 32 + h * 8);
  bf16x8 qf3 = *(const bf16x8*)(Qrow + 48 + h * 8);

  f32x16 o0 = {}, o1 = {};
  float m_run = -INFINITY, l_run = 0.f;

  stageKV(0, 0);
  stageKV(1, 1);
  int slot = 0;

#pragma unroll 1
  for (int kt = 0; kt < NT; ++kt) {
    const int kbase = kt * 64;
    if (kt + 1 < NT) {
      asm volatile("s_waitcnt vmcnt(2)" ::: "memory");
    } else {
      asm volatile("s_waitcnt vmcnt(0)" ::: "memory");
    }
    __builtin_amdgcn_sched_barrier(0);
    barrier_asm();
    if (kt + 2 < NT) {
      int ns = slot + 2; if (ns >= 3) ns -= 3;
      stageKV(kt + 2, ns);
    }

    if (kbase <= qbase + w * 32 + 31) {
      const char* KsB = (const char*)&Ks[slot][0];
      const char* VsB = (const char*)&Vs[slot][0];

      f32x16 s0 = {}, s1 = {};
      __builtin_amdgcn_s_setprio(1);
#pragma unroll
      for (int ds = 0; ds < 4; ++ds) {
        bf16x8 k0 = *(const bf16x8*)(KsB + ((lr * 128 + ds * 32 + h * 16) ^ kxor));
        bf16x8 k1 = *(const bf16x8*)(KsB + (((lr + 32) * 128 + ds * 32 + h * 16) ^ kxor));
        bf16x8 qd = (ds == 0) ? qf0 : (ds == 1) ? qf1 : (ds == 2) ? qf2 : qf3;
        s0 = mfma32(k0, qd, s0);
        s1 = mfma32(k1, qd, s1);
      }
      __builtin_amdgcn_s_setprio(0);

      if (kbase + 63 > qbase + w * 32) {
#pragma unroll
        for (int r = 0; r < 16; ++r) {
          int tk0 = kbase + (r & 3) + 8 * (r >> 2) + 4 * h;
          if (tk0 > tqg) s0[r] = -INFINITY;
          if (tk0 + 32 > tqg) s1[r] = -INFINITY;
        }
      }

      float mx = s0[0];
#pragma unroll
      for (int r = 1; r < 16; ++r) mx = fmaxf(mx, s0[r]);
#pragma unroll
      for (int r = 0; r < 16; ++r) mx = fmaxf(mx, s1[r]);
      mx = fmaxf(mx, __shfl_xor(mx, 32));
      if (!__all(mx - m_run <= 256.f)) {
        float mn = fmaxf(m_run, mx);
        float fac = __builtin_amdgcn_exp2f((m_run - mn) * C2);
        l_run *= fac;
#pragma unroll
        for (int r = 0; r < 16; ++r) { o0[r] *= fac; o1[r] *= fac; }
        m_run = mn;
      }
      float sum = 0.f;
#pragma unroll
      for (int r = 0; r < 16; ++r) {
        s0[r] = __builtin_amdgcn_exp2f((s0[r] - m_run) * C2);
        s1[r] = __builtin_amdgcn_exp2f((s1[r] - m_run) * C2);
        sum += s0[r] + s1[r];
      }
      sum += __shfl_xor(sum, 32);
      l_run += sum;

      __builtin_amdgcn_s_setprio(1);
#pragma unroll
      for (int blk = 0; blk < 4; ++blk) {
        f32x16& sv = (blk < 2) ? s0 : s1;
        const int off = (blk & 1) * 8;
        unsigned u0 = cvt_pk_bf16(sv[off + 0], sv[off + 1]);
        unsigned u1 = cvt_pk_bf16(sv[off + 2], sv[off + 3]);
        unsigned u2 = cvt_pk_bf16(sv[off + 4], sv[off + 5]);
        unsigned u3 = cvt_pk_bf16(sv[off + 6], sv[off + 7]);
        pl32swap(u0, u2);
        pl32swap(u1, u3);
        union { unsigned u[4]; bf16x8 v; } pb;
        pb.u[0] = u0; pb.u[1] = u1; pb.u[2] = u2; pb.u[3] = u3;
        bf16x8 v0 = *(const bf16x8*)(VsB + ((lr * 128 + blk * 32 + h * 16) ^ kxor));
        bf16x8 v1 = *(const bf16x8*)(VsB + (((lr + 32) * 128 + blk * 32 + h * 16) ^ kxor));
        o0 = mfma32(v0, pb.v, o0);
        o1 = mfma32(v1, pb.v, o1);
      }
      __builtin_amdgcn_s_setprio(0);
    }
    slot = (slot == 2) ? 0 : slot + 1;
  }

  const float inv_l = 1.0f / l_run;
  float* orow = out + ((size_t)b * T_ + tqg) * E_ + hh * 64;
#pragma unroll
  for (int d0i = 0; d0i < 2; ++d0i) {
#pragma unroll
    for (int qd = 0; qd < 4; ++qd) {
      float4 v;
      const f32x16& ac = d0i ? o1 : o0;
      v.x = ac[qd * 4 + 0] * inv_l;
      v.y = ac[qd * 4 + 1] * inv_l;
      v.z = ac[qd * 4 + 2] * inv_l;
      v.w = ac[qd * 4 + 3] * inv_l;
      *(float4*)(orow + d0i * 32 + qd * 8 + 4 * h) = v;
    }
  }
}

extern "C" void kernel_launch(void* const* d_in, const int* in_sizes, int n_in,
                              void* d_out, int out_size, void* d_ws, size_t ws_size,
                              hipStream_t stream) {
  const float* x = (const float*)d_in[0];
  const float* Wq = (const float*)d_in[1];
  const float* Wk = (const float*)d_in[2];
  const float* Wv = (const float*)d_in[3];
  float* out = (float*)d_out;

  char* ws = (char*)d_ws;
  __bf16* Xb = (__bf16*)ws;                    // 16 MiB
  __bf16* Wt = (__bf16*)(ws + (16u << 20));    //  6 MiB
  __bf16* Qb = (__bf16*)(ws + (22u << 20));    // 16 MiB
  __bf16* Kb = (__bf16*)(ws + (38u << 20));    // 16 MiB
  __bf16* Vt = (__bf16*)(ws + (54u << 20));    // 16 MiB

  cvt_x_kernel<<<8192, 256, 0, stream>>>(x, Xb);
  cvt_w_kernel<<<dim3(16, 16, 3), 256, 0, stream>>>(Wq, Wk, Wv, Wt);
  qkv_gemm_kernel<<<dim3(64, 4, 3), 512, 0, stream>>>(Xb, Wt, Qb, Kb, Vt);
  attn_kernel<<<dim3(512), 512, 0, stream>>>(Qb, Kb, Vt, out);
}